// Round 13
// baseline (1199.770 us; speedup 1.0000x reference)
//
#include <hip/hip_runtime.h>

typedef unsigned short u16;
typedef __attribute__((ext_vector_type(4))) unsigned short u16x4;
typedef __attribute__((ext_vector_type(8))) unsigned short u16x8;
typedef __attribute__((ext_vector_type(8))) short bf16x8;
typedef __attribute__((ext_vector_type(4))) float f32x4;
typedef __attribute__((ext_vector_type(16))) float f32x16;

__device__ __forceinline__ u16 f2b(float f) {
  union { float f; unsigned u; } v; v.f = f;
  unsigned r = (v.u + 0x7fffu + ((v.u >> 16) & 1u)) >> 16;
  return (u16)r;
}

// ---------------- elementwise f32 -> bf16 (8/thread) ----------------
__global__ void k_f2b(const float* __restrict__ in, u16* __restrict__ out, size_t n8) {
  size_t i = (size_t)blockIdx.x * blockDim.x + threadIdx.x;
  if (i >= n8) return;
  const f32x4* p = (const f32x4*)in + i * 2;
  f32x4 a = p[0], b = p[1];
  u16x8 o;
  o[0] = f2b(a[0]); o[1] = f2b(a[1]); o[2] = f2b(a[2]); o[3] = f2b(a[3]);
  o[4] = f2b(b[0]); o[5] = f2b(b[1]); o[6] = f2b(b[2]); o[7] = f2b(b[3]);
  *((u16x8*)out + i) = o;
}

// ---------------- transpose f32[R][C] -> bf16[Cp][R] (zero-pad rows C..Cp) ----
__global__ void k_trans_f2b(const float* __restrict__ in, u16* __restrict__ out,
                            int R, int C, int Cp) {
  __shared__ float t[32][33];
  int bx = blockIdx.x, by = blockIdx.y;
  int x = bx * 32 + threadIdx.x;
  int y0 = by * 32 + threadIdx.y;
#pragma unroll
  for (int j = 0; j < 32; j += 8) {
    int y = y0 + j;
    t[threadIdx.y + j][threadIdx.x] = (x < C && y < R) ? in[(size_t)y * C + x] : 0.f;
  }
  __syncthreads();
  int ox = by * 32 + threadIdx.x;
  int oy0 = bx * 32 + threadIdx.y;
#pragma unroll
  for (int j = 0; j < 32; j += 8) {
    int oy = oy0 + j;
    if (oy < Cp && ox < R) out[(size_t)oy * R + ox] = f2b(t[threadIdx.x][threadIdx.y + j]);
  }
}

// =====================================================================
// 256x256 8-phase GEMM, 32x32x16 MFMA, OPERAND-ORDER-LINEAR LDS:
// each frag (row-block b in 0..7, KH in 0..1) of a 16KB slot occupies a
// contiguous 1KB block; lane l reads byte base+16l -> conflict-free by
// construction (identical pattern to global_load_lds writes). Staging
// realizes the layout purely via the per-lane GLOBAL source decode
// (rule #21): thread t stages chunk q=t / q=512+t, with
//   b=q>>7, KH=(q>>6)&1, g2=(q>>5)&1, r31=q&31
//   -> src row = b*32+r31, k-chunk = 2KH+g2.
// Schedule skeleton (8 phases, 6/6 reads, VM6, single barrier, aX/aY
// prefetch, 8x8 super-tile + XCD swizzle) = round-12 verbatim.
// Operand/epilogue math = round-4 (correctness-verified on HW).
// =====================================================================
#define VM4 asm volatile("s_waitcnt vmcnt(4)" ::: "memory")
#define VM6 asm volatile("s_waitcnt vmcnt(6)" ::: "memory")
#define NOVM ((void)0)
#define NOSTMT ((void)0)

#define MFMA32 __builtin_amdgcn_mfma_f32_32x32x16_bf16

// prefetch KH0 A-frags of slot SLOT into DST[0..3]
#define LDK0(DST, SLOT)                                   \
  DST[0] = *(const bf16x8*)&lds[(SLOT) + oA0[0]];         \
  DST[1] = *(const bf16x8*)&lds[(SLOT) + oA0[1]];         \
  DST[2] = *(const bf16x8*)&lds[(SLOT) + oA0[2]];         \
  DST[3] = *(const bf16x8*)&lds[(SLOT) + oA0[3]];

// NH0 phase: read ACUR[4..7] (KH1 A) + B(KH0) x2; MFMA KH0 (8x 32x32)
#define P_N0(TB, KK, ACUR, STAGE_STMT, VMSTMT)                        \
  {                                                                   \
    const int so = (TB * 2 + KK) * 8192;                              \
    ACUR[4] = *(const bf16x8*)&lds[so + oA1[0]];                      \
    ACUR[5] = *(const bf16x8*)&lds[so + oA1[1]];                      \
    ACUR[6] = *(const bf16x8*)&lds[so + oA1[2]];                      \
    ACUR[7] = *(const bf16x8*)&lds[so + oA1[3]];                      \
    bf16x8 b0 = *(const bf16x8*)&lds[32768 + so + oB0[0]];            \
    bf16x8 b1 = *(const bf16x8*)&lds[32768 + so + oB0[1]];            \
    STAGE_STMT;                                                       \
    VMSTMT;                                                           \
    __builtin_amdgcn_s_barrier();                                     \
    __builtin_amdgcn_s_setprio(1);                                    \
    acc[0][0] = MFMA32(ACUR[0], b0, acc[0][0], 0, 0, 0);              \
    acc[0][1] = MFMA32(ACUR[0], b1, acc[0][1], 0, 0, 0);              \
    acc[1][0] = MFMA32(ACUR[1], b0, acc[1][0], 0, 0, 0);              \
    acc[1][1] = MFMA32(ACUR[1], b1, acc[1][1], 0, 0, 0);              \
    acc[2][0] = MFMA32(ACUR[2], b0, acc[2][0], 0, 0, 0);              \
    acc[2][1] = MFMA32(ACUR[2], b1, acc[2][1], 0, 0, 0);              \
    acc[3][0] = MFMA32(ACUR[3], b0, acc[3][0], 0, 0, 0);              \
    acc[3][1] = MFMA32(ACUR[3], b1, acc[3][1], 0, 0, 0);              \
    __builtin_amdgcn_s_setprio(0);                                    \
  }

// NH1 phase: read B(KH1) x2 (+PRE/POST prefetch of next KH0 A); MFMA KH1
#define P_N1(TB, KK, ACUR, PRE_STMT, STAGE_STMT, VMSTMT, POST_STMT)   \
  {                                                                   \
    const int so = (TB * 2 + KK) * 8192;                              \
    bf16x8 b2 = *(const bf16x8*)&lds[32768 + so + oB1[0]];            \
    bf16x8 b3 = *(const bf16x8*)&lds[32768 + so + oB1[1]];            \
    PRE_STMT;                                                         \
    STAGE_STMT;                                                       \
    VMSTMT;                                                           \
    __builtin_amdgcn_s_barrier();                                     \
    POST_STMT;                                                        \
    __builtin_amdgcn_s_setprio(1);                                    \
    acc[0][0] = MFMA32(ACUR[4], b2, acc[0][0], 0, 0, 0);              \
    acc[0][1] = MFMA32(ACUR[4], b3, acc[0][1], 0, 0, 0);              \
    acc[1][0] = MFMA32(ACUR[5], b2, acc[1][0], 0, 0, 0);              \
    acc[1][1] = MFMA32(ACUR[5], b3, acc[1][1], 0, 0, 0);              \
    acc[2][0] = MFMA32(ACUR[6], b2, acc[2][0], 0, 0, 0);              \
    acc[2][1] = MFMA32(ACUR[6], b3, acc[2][1], 0, 0, 0);              \
    acc[3][0] = MFMA32(ACUR[7], b2, acc[3][0], 0, 0, 0);              \
    acc[3][1] = MFMA32(ACUR[7], b3, acc[3][1], 0, 0, 0);              \
    __builtin_amdgcn_s_setprio(0);                                    \
  }

template <int OUTB, int ACT, int BIASM>
__global__ __launch_bounds__(512, 2)
void gemm8(const u16* __restrict__ A, const u16* __restrict__ Bt,
           const float* __restrict__ bias, int bias_n,
           void* __restrict__ Cout, int M, int Nc, int K) {
  __shared__ __align__(16) u16 lds[65536];  // A slots [0,32768), B slots [32768,65536)

  const int nbn = Nc >> 8, nbm = M >> 8;
  const int nwg = nbm * nbn;
  int bid = blockIdx.x;
  {  // bijective XCD swizzle (m204)
    int q = nwg >> 3, r = nwg & 7;
    int xcd = bid & 7, loc = bid >> 3;
    bid = (xcd < r ? xcd * (q + 1) : r * (q + 1) + (xcd - r) * q) + loc;
  }
  // 8x8 super-tile decode (round-12 verified: FETCH 970->394 MB)
  const int ns_n = nbn >> 3;
  const int sid = bid >> 6, idx = bid & 63;
  const int bm = ((sid / ns_n) << 3) + (idx >> 3);
  const int bn = ((sid % ns_n) << 3) + (idx & 7);
  const size_t row0 = (size_t)bm << 8, col0 = (size_t)bn << 8;

  const int tid = threadIdx.x;
  const int lane = tid & 63, wid = tid >> 6;
  const int wr = (wid >> 2) * 128, wc = (wid & 3) * 64;  // 2x4 waves, 128x64 each
  const int l31 = lane & 31, g2 = lane >> 5;

  // frag read offsets (u16): frag (b, KH) at chunk b*128 + KH*64 + lane
  int oA0[4], oA1[4], oB0[2], oB1[2];
#pragma unroll
  for (int mt = 0; mt < 4; ++mt) {
    int b = (wid >> 2) * 4 + mt;               // (wr + mt*32) >> 5
    oA0[mt] = b * 1024 + lane * 8;             // KH=0
    oA1[mt] = b * 1024 + 512 + lane * 8;       // KH=1
  }
#pragma unroll
  for (int nt = 0; nt < 2; ++nt) {
    int b = (wid & 3) * 2 + nt;                // (wc + nt*32) >> 5
    oB0[nt] = b * 1024 + lane * 8;
    oB1[nt] = b * 1024 + 512 + lane * 8;
  }

  // staging source decode (operand-order layout, rule #21):
  // call0 stages chunk q=tid, call1 chunk q=tid+512 (row +128, same k-chunk)
  const int sb = tid >> 7;                     // row block 0..3
  const int sKH = (tid >> 6) & 1, sg2 = (tid >> 5) & 1, sr = tid & 31;
  const int srow = sb * 32 + sr;
  const int skc = sKH * 2 + sg2;               // k-chunk 0..3 within 32-k slot
  const u16* As0 = A + (row0 + srow) * (size_t)K + skc * 8;
  const u16* Bs0 = Bt + (col0 + srow) * (size_t)K + skc * 8;
  const size_t rstep = (size_t)128 * K;        // +128 rows for call1

  auto stA = [&](int tb, int kk, int t) {
    size_t off = (size_t)t * 64 + kk * 32;
    u16* l = (u16*)lds + (tb * 2 + kk) * 8192 + wid * 512;
    __builtin_amdgcn_global_load_lds((const __attribute__((address_space(1))) void*)(As0 + off),
                                     (__attribute__((address_space(3))) void*)l, 16, 0, 0);
    __builtin_amdgcn_global_load_lds((const __attribute__((address_space(1))) void*)(As0 + rstep + off),
                                     (__attribute__((address_space(3))) void*)(l + 4096), 16, 0, 0);
  };
  auto stB = [&](int tb, int kk, int t) {
    size_t off = (size_t)t * 64 + kk * 32;
    u16* l = (u16*)lds + 32768 + (tb * 2 + kk) * 8192 + wid * 512;
    __builtin_amdgcn_global_load_lds((const __attribute__((address_space(1))) void*)(Bs0 + off),
                                     (__attribute__((address_space(3))) void*)l, 16, 0, 0);
    __builtin_amdgcn_global_load_lds((const __attribute__((address_space(1))) void*)(Bs0 + rstep + off),
                                     (__attribute__((address_space(3))) void*)(l + 4096), 16, 0, 0);
  };

  f32x16 acc[4][2];
#pragma unroll
  for (int mt = 0; mt < 4; ++mt)
#pragma unroll
    for (int nt = 0; nt < 2; ++nt)
#pragma unroll
      for (int i = 0; i < 16; ++i) acc[mt][nt][i] = 0.f;

  bf16x8 aX[8], aY[8];

  const int NT = K >> 6;       // 64-wide K tiles
  const int NI = K >> 7;       // 2 tiles per iteration

  // prologue: tile0 (both halves -> tb0), tile1 k0 -> tb1
  stA(0, 0, 0); stB(0, 0, 0);
  stA(0, 1, 0); stB(0, 1, 0);
  stA(1, 0, 1); stB(1, 0, 1);
  VM4;  // tile0 fully landed; tile1.k0 may be in flight
  __builtin_amdgcn_s_barrier();
  __builtin_amdgcn_sched_barrier(0);
  LDK0(aX, 0)  // slot (0,0) KH0 A-frags

  for (int it = 0; it < NI; ++it) {
    const int u = 2 * it;
    const int t1 = u + 1;
    const int t2 = (u + 2 < NT) ? u + 2 : NT - 1;
    const int t3 = (u + 3 < NT) ? u + 3 : NT - 1;
    // p1: TB0 KK0 NH0
    P_N0(0, 0, aX, stA(1, 1, t1), NOVM)
    // p2: TB0 KK0 NH1; VM6 then pre-read aY<-(0,1) KH0
    P_N1(0, 0, aX, VM6; LDK0(aY, 8192), stB(1, 1, t1), NOVM, NOSTMT)
    // p3: TB0 KK1 NH0
    P_N0(0, 1, aY, stA(0, 0, t2), NOVM)
    // p4: TB0 KK1 NH1; VM6; post-read aX<-(1,0) KH0
    P_N1(0, 1, aY, NOSTMT, stB(0, 0, t2), VM6,
         __builtin_amdgcn_sched_barrier(0); LDK0(aX, 16384))
    // p5: TB1 KK0 NH0
    P_N0(1, 0, aX, stA(0, 1, t2), NOVM)
    // p6: TB1 KK0 NH1; VM6 then pre-read aY<-(1,1) KH0
    P_N1(1, 0, aX, VM6; LDK0(aY, 24576), stB(0, 1, t2), NOVM, NOSTMT)
    // p7: TB1 KK1 NH0
    P_N0(1, 1, aY, stA(1, 0, t3), NOVM)
    // p8: TB1 KK1 NH1; VM6; post-read aX<-(0,0) KH0 (tile t2)
    P_N1(1, 1, aY, NOSTMT, stB(1, 0, t3), VM6,
         __builtin_amdgcn_sched_barrier(0); LDK0(aX, 0))
  }

  // epilogue: 32x32 C/D layout (m74/m101, round-4 correctness-verified):
  // col = lane&31, row = (reg&3) + 8*(reg>>2) + 4*(lane>>5)
#pragma unroll
  for (int mt = 0; mt < 4; ++mt) {
#pragma unroll
    for (int nt = 0; nt < 2; ++nt) {
      size_t cc = col0 + wc + nt * 32 + l31;
      float bc = (BIASM == 2) ? bias[cc] : 0.f;
      size_t base_r = row0 + wr + mt * 32 + g2 * 4;
#pragma unroll
      for (int rg = 0; rg < 16; ++rg) {
        size_t r = base_r + (rg & 3) + 8 * (rg >> 2);
        float v = acc[mt][nt][rg];
        if (BIASM == 1) v += (r < (size_t)bias_n) ? bias[r] : 0.f;
        if (BIASM == 2) v += bc;
        if (ACT == 1) v = fmaxf(v, 0.f);
        if (OUTB) ((u16*)Cout)[r * (size_t)Nc + cc] = f2b(v);
        else      ((float*)Cout)[r * (size_t)Nc + cc] = v;
      }
    }
  }
}

// ------------- 128x128 split-K GEMM: Cpart[s] = A[:,k0:k0+Klen] @ Bt^T -------
// Only writes the live region [0,mw) x [0,nw) of each partial.
__global__ __launch_bounds__(256)
void gemm_splitk(const u16* __restrict__ A, const u16* __restrict__ Bt,
                 float* __restrict__ Cpart, int M, int Nc, int Kstride, int Klen,
                 int mw, int nw) {
  constexpr int BM = 128, BN = 128, BK = 32;
  __shared__ __align__(16) u16 As[2][BM * BK];
  __shared__ __align__(16) u16 Bs[2][BN * BK];

  const int nbn = Nc / BN;
  const int bid = blockIdx.x;
  const int s = blockIdx.y;
  const int k0 = s * Klen;
  const int bm = bid / nbn, bn = bid % nbn;
  const size_t row0 = (size_t)bm * BM, col0 = (size_t)bn * BN;

  const int tid = threadIdx.x;
  const int lane = tid & 63, wid = tid >> 6;
  const int wr = (wid >> 1) << 6, wc = (wid & 1) << 6;

  f32x4 acc[4][4];
#pragma unroll
  for (int m = 0; m < 4; ++m)
#pragma unroll
    for (int n = 0; n < 4; ++n)
#pragma unroll
      for (int i = 0; i < 4; ++i) acc[m][n][i] = 0.f;

  const int NT = Klen / BK;

  auto stage = [&](int buf, int t) {
    const int kk = k0 + t * BK;
#pragma unroll
    for (int i = 0; i < 2; ++i) {
      int lin = i * 256 + tid;
      int r = lin >> 2, c = lin & 3;
      int cs = c ^ ((r >> 1) & 3);
      const u16* ga = A + (row0 + r) * (size_t)Kstride + (size_t)(kk + cs * 8);
      u16* la = (u16*)As[buf] + (size_t)(i * 256 + (wid << 6)) * 8;
      __builtin_amdgcn_global_load_lds((const __attribute__((address_space(1))) void*)ga,
                                       (__attribute__((address_space(3))) void*)la, 16, 0, 0);
      const u16* gb = Bt + (col0 + r) * (size_t)Kstride + (size_t)(kk + cs * 8);
      u16* lb = (u16*)Bs[buf] + (size_t)(i * 256 + (wid << 6)) * 8;
      __builtin_amdgcn_global_load_lds((const __attribute__((address_space(1))) void*)gb,
                                       (__attribute__((address_space(3))) void*)lb, 16, 0, 0);
    }
  };

  stage(0, 0);
  __syncthreads();
  int cur = 0;
  for (int t = 0; t < NT; ++t) {
    if (t + 1 < NT) stage(cur ^ 1, t + 1);
    const int g = lane >> 4, r15 = lane & 15;
    bf16x8 af[4], bfv[4];
#pragma unroll
    for (int m = 0; m < 4; ++m) {
      int rr = wr + m * 16 + r15;
      int sc = g ^ ((rr >> 1) & 3);
      af[m] = *(const bf16x8*)(As[cur] + rr * BK + sc * 8);
    }
#pragma unroll
    for (int n = 0; n < 4; ++n) {
      int rr = wc + n * 16 + r15;
      int sc = g ^ ((rr >> 1) & 3);
      bfv[n] = *(const bf16x8*)(Bs[cur] + rr * BK + sc * 8);
    }
#pragma unroll
    for (int m = 0; m < 4; ++m)
#pragma unroll
      for (int n = 0; n < 4; ++n)
        acc[m][n] = __builtin_amdgcn_mfma_f32_16x16x32_bf16(af[m], bfv[n], acc[m][n], 0, 0, 0);
    __syncthreads();
    cur ^= 1;
  }

  float* Cp = Cpart + (size_t)s * M * Nc;
  const int rB = (lane >> 4) << 2;
  const int cB = lane & 15;
#pragma unroll
  for (int m = 0; m < 4; ++m) {
#pragma unroll
    for (int n = 0; n < 4; ++n) {
      size_t rr0 = row0 + wr + m * 16 + rB;
      size_t cc = col0 + wc + n * 16 + cB;
      if ((int)rr0 < mw && (int)cc < nw) {
#pragma unroll
        for (int i = 0; i < 4; ++i)
          Cp[(rr0 + i) * (size_t)Nc + cc] = acc[m][n][i];
      }
    }
  }
}

// ---- reduce 8 partials [128][8192] rows<64 + b2 -> t2T bf16 (rows>=64 zero) ----
__global__ void k_red3(const float* __restrict__ part, const float* __restrict__ b2,
                       u16* __restrict__ t2T) {
  int i = blockIdx.x * 256 + threadIdx.x;
  size_t idx = (size_t)i * 4;
  int r = (int)(idx >> 13);
  u16x4 o;
  if (r < 64) {
    f32x4 s = *(const f32x4*)(part + idx);
#pragma unroll
    for (int ss = 1; ss < 8; ++ss) {
      f32x4 p = *(const f32x4*)(part + (size_t)ss * 1048576 + idx);
      s[0] += p[0]; s[1] += p[1]; s[2] += p[2]; s[3] += p[3];
    }
    float b = b2[r];
    o[0] = f2b(s[0] + b); o[1] = f2b(s[1] + b); o[2] = f2b(s[2] + b); o[3] = f2b(s[3] + b);
  } else {
    o[0] = 0; o[1] = 0; o[2] = 0; o[3] = 0;
  }
  *(u16x4*)(t2T + idx) = o;
}

// ---- fused: reduce 8 partials -> code = tanh(10*sum); LN + RBF + silu -> Acat ----
__global__ void k_red4kan(const float* __restrict__ part, const float* __restrict__ lng,
                          const float* __restrict__ lnb, float* __restrict__ code,
                          u16* __restrict__ Acat) {
  int row = blockIdx.x * 4 + (threadIdx.x >> 6);
  int c = threadIdx.x & 63;
  size_t idx = (size_t)row * 128 + c;
  float sm = 0.f;
#pragma unroll
  for (int ss = 0; ss < 8; ++ss) sm += part[(size_t)ss * 1048576 + idx];
  float xv = tanhf(10.f * sm);
  code[(size_t)row * 64 + c] = xv;
  float s = xv, s2 = xv * xv;
#pragma unroll
  for (int m = 32; m; m >>= 1) { s += __shfl_xor(s, m); s2 += __shfl_xor(s2, m); }
  float mean = s * 0.015625f;
  float var = s2 * 0.015625f - mean * mean;
  float z = (xv - mean) * rsqrtf(var + 1e-5f) * lng[c] + lnb[c];
  u16x8 o;
#pragma unroll
  for (int gi = 0; gi < 8; ++gi) {
    float gp = -2.f + gi * (4.f / 7.f);
    float d = (z - gp) * (7.f / 4.f);
    o[gi] = f2b(expf(-d * d));
  }
  *(u16x8*)(Acat + (size_t)row * 640 + c * 8) = o;
  float si = xv / (1.f + expf(-xv));
  Acat[(size_t)row * 640 + 512 + c] = f2b(si);
  Acat[(size_t)row * 640 + 576 + c] = 0;  // K-pad
}

// ---------------- Bcat[8192][640] = [Ws | Wb | 0] bf16 ----------------
__global__ void k_bcat(const float* __restrict__ Ws, const float* __restrict__ Wb,
                       u16* __restrict__ Bcat) {
  int i = blockIdx.x * 256 + threadIdx.x;
  int n = i / 80, j = i % 80;
  u16x8 o;
  if (j < 72) {
    const float* src = (j < 64) ? (Ws + (size_t)n * 512 + j * 8)
                                : (Wb + (size_t)n * 64 + (j - 64) * 8);
    f32x4 a = *(const f32x4*)src, b = *(const f32x4*)(src + 4);
    o[0] = f2b(a[0]); o[1] = f2b(a[1]); o[2] = f2b(a[2]); o[3] = f2b(a[3]);
    o[4] = f2b(b[0]); o[5] = f2b(b[1]); o[6] = f2b(b[2]); o[7] = f2b(b[3]);
  } else {
    o = (u16x8)0;
  }
  *(u16x8*)(Bcat + (size_t)n * 640 + j * 8) = o;
}

extern "C" void kernel_launch(void* const* d_in, const int* in_sizes, int n_in,
                              void* d_out, int out_size, void* d_ws, size_t ws_size,
                              hipStream_t stream) {
  const float* x   = (const float*)d_in[0];
  const float* G   = (const float*)d_in[1];
  const float* W1  = (const float*)d_in[2];
  const float* b1  = (const float*)d_in[3];
  const float* W2  = (const float*)d_in[4];
  const float* b2  = (const float*)d_in[5];
  const float* lng = (const float*)d_in[6];
  const float* lnb = (const float*)d_in[7];
  const float* Ws  = (const float*)d_in[8];
  const float* Wb  = (const float*)d_in[9];
  const float* bb  = (const float*)d_in[10];

  uint8_t* w = (uint8_t*)d_ws;
  u16* G_b  = (u16*)w;                   // [8192][8192] bf16  [0,128M)
  u16* x_b  = (u16*)(w + 134217728);     // [8192][4096] bf16  [128M,192M)
  u16* h_b  = x_b;                       // reuse after step1
  uint8_t* r2 = w + 201326592;           // [192M,224M)
  u16* W1T  = (u16*)r2;                  // [4096][4096] (dead after step1)
  u16* t2T  = (u16*)r2;                  // [128][8192]  (after W1T dead)
  u16* Acat = (u16*)(r2 + 8388608);      // [8192][640]
  u16* Bcat = (u16*)(r2 + 18874368);     // [8192][640]
  u16* t1T  = (u16*)(w + 234881024);     // [4096][8192] (dead after step2)
  u16* W2T  = t1T;                       // [128][4096] reuses t1T space
  float* part = (float*)(w + 234881024 + 2097152);  // 8x[128][8192] f32

  float* code_out = (float*)d_out;              // [8192][64]
  float* out1 = (float*)d_out + 524288;         // [8192][8192]

  // conversions
  k_f2b<<<32768, 256, 0, stream>>>(G, G_b, 8388608);
  k_f2b<<<16384, 256, 0, stream>>>(x, x_b, 4194304);
  k_trans_f2b<<<dim3(128, 128), dim3(32, 8), 0, stream>>>(W1, W1T, 4096, 4096, 4096);

  // step1: t1T[4096][8192] = W1T @ x^T + b1(row)   (nbm=16, nbn=32)
  gemm8<1, 0, 1><<<512, 512, 0, stream>>>(W1T, x_b, b1, 4096, t1T, 4096, 8192, 4096);
  // step2: h[8192][4096] = relu(G @ t1)            (nbm=32, nbn=16)
  gemm8<1, 1, 0><<<512, 512, 0, stream>>>(G_b, t1T, nullptr, 0, h_b, 8192, 4096, 8192);
  // W2T [128][4096] (rows 64..127 zero)
  k_trans_f2b<<<dim3(4, 128), dim3(32, 8), 0, stream>>>(W2, W2T, 4096, 64, 128);
  // step3 (split-K x8): part[s] = W2T @ h^T chunk (rows<64 live)
  gemm_splitk<<<dim3(64, 8), 256, 0, stream>>>(W2T, h_b, part, 128, 8192, 4096, 512, 64, 8192);
  // reduce + b2 -> t2T bf16
  k_red3<<<1024, 256, 0, stream>>>(part, b2, t2T);
  // step4 (split-K x8): part[s] = G @ t2 chunk (cols<64 live)
  gemm_splitk<<<dim3(64, 8), 256, 0, stream>>>(G_b, t2T, part, 8192, 128, 8192, 1024, 8192, 64);
  // fused reduce -> code = tanh(10*feat); LN + RBF + silu -> Acat
  k_red4kan<<<2048, 256, 0, stream>>>(part, lng, lnb, code_out, Acat);
  // Bcat = [Ws | Wb | 0]
  k_bcat<<<2560, 256, 0, stream>>>(Ws, Wb, Bcat);
  // final: out = relu(Acat @ Bcat^T + bb(col))     (nbm=32, nbn=32)
  gemm8<0, 1, 2><<<1024, 512, 0, stream>>>(Acat, Bcat, bb, 8192, out1, 8192, 8192, 640);
}

// Round 14
// 961.012 us; speedup vs baseline: 1.2484x; 1.2484x over previous
//
#include <hip/hip_runtime.h>

typedef unsigned short u16;
typedef __attribute__((ext_vector_type(4))) unsigned short u16x4;
typedef __attribute__((ext_vector_type(8))) unsigned short u16x8;
typedef __attribute__((ext_vector_type(8))) short bf16x8;
typedef __attribute__((ext_vector_type(4))) float f32x4;

__device__ __forceinline__ u16 f2b(float f) {
  union { float f; unsigned u; } v; v.f = f;
  unsigned r = (v.u + 0x7fffu + ((v.u >> 16) & 1u)) >> 16;
  return (u16)r;
}

// ---------------- elementwise f32 -> bf16 (8/thread) ----------------
__global__ void k_f2b(const float* __restrict__ in, u16* __restrict__ out, size_t n8) {
  size_t i = (size_t)blockIdx.x * blockDim.x + threadIdx.x;
  if (i >= n8) return;
  const f32x4* p = (const f32x4*)in + i * 2;
  f32x4 a = p[0], b = p[1];
  u16x8 o;
  o[0] = f2b(a[0]); o[1] = f2b(a[1]); o[2] = f2b(a[2]); o[3] = f2b(a[3]);
  o[4] = f2b(b[0]); o[5] = f2b(b[1]); o[6] = f2b(b[2]); o[7] = f2b(b[3]);
  *((u16x8*)out + i) = o;
}

// ---------------- transpose f32[R][C] -> bf16[Cp][R] (zero-pad rows C..Cp) ----
__global__ void k_trans_f2b(const float* __restrict__ in, u16* __restrict__ out,
                            int R, int C, int Cp) {
  __shared__ float t[32][33];
  int bx = blockIdx.x, by = blockIdx.y;
  int x = bx * 32 + threadIdx.x;
  int y0 = by * 32 + threadIdx.y;
#pragma unroll
  for (int j = 0; j < 32; j += 8) {
    int y = y0 + j;
    t[threadIdx.y + j][threadIdx.x] = (x < C && y < R) ? in[(size_t)y * C + x] : 0.f;
  }
  __syncthreads();
  int ox = by * 32 + threadIdx.x;
  int oy0 = bx * 32 + threadIdx.y;
#pragma unroll
  for (int j = 0; j < 32; j += 8) {
    int oy = oy0 + j;
    if (oy < Cp && ox < R) out[(size_t)oy * R + ox] = f2b(t[threadIdx.x][threadIdx.y + j]);
  }
}

// =====================================================================
// 256x256 8-phase GEMM (round-12 verified optimum): 16x16x32 MFMA,
// 0-conflict chunk-XOR LDS, counted VM6, single barrier per phase,
// setprio, aX/aY A-frag prefetch, 8x8 super-tile block clustering
// (FETCH 970->394 MB, MfmaUtil 64%) + bijective XCD swizzle.
// =====================================================================
#define VM4 asm volatile("s_waitcnt vmcnt(4)" ::: "memory")
#define VM6 asm volatile("s_waitcnt vmcnt(6)" ::: "memory")
#define NOVM ((void)0)
#define NOSTMT ((void)0)

#define MFMA_BF16 __builtin_amdgcn_mfma_f32_16x16x32_bf16

#define LDA4(DST, SLOT, J0)                                   \
  DST[J0 + 0] = *(const bf16x8*)&lds[(SLOT) + oA[J0 + 0]];    \
  DST[J0 + 1] = *(const bf16x8*)&lds[(SLOT) + oA[J0 + 1]];    \
  DST[J0 + 2] = *(const bf16x8*)&lds[(SLOT) + oA[J0 + 2]];    \
  DST[J0 + 3] = *(const bf16x8*)&lds[(SLOT) + oA[J0 + 3]];

// NH0 phase: read ACUR[4..7] + B[0,1]; MFMA n=0,1 (all m).
#define P_N0(TB, KK, ACUR, STAGE_STMT, VMSTMT)                       \
  {                                                                  \
    const int so = (TB * 2 + KK) * 8192;                             \
    LDA4(ACUR, so, 4)                                                \
    bf16x8 b0 = *(const bf16x8*)&lds[32768 + so + oB[0]];            \
    bf16x8 b1 = *(const bf16x8*)&lds[32768 + so + oB[1]];            \
    STAGE_STMT;                                                      \
    VMSTMT;                                                          \
    __builtin_amdgcn_s_barrier();                                    \
    __builtin_amdgcn_s_setprio(1);                                   \
    _Pragma("unroll") for (int m = 0; m < 8; ++m) {                  \
      acc[m][0] = MFMA_BF16(ACUR[m], b0, acc[m][0], 0, 0, 0);        \
      acc[m][1] = MFMA_BF16(ACUR[m], b1, acc[m][1], 0, 0, 0);        \
    }                                                                \
    __builtin_amdgcn_s_setprio(0);                                   \
  }

// NH1 phase: read B[2,3] (+optional PRE: wait + prefetch next A[0..3]);
// optional POST prefetch after barrier; MFMA n=2,3 (all m).
#define P_N1(TB, KK, ACUR, PRE_STMT, STAGE_STMT, VMSTMT, POST_STMT)  \
  {                                                                  \
    const int so = (TB * 2 + KK) * 8192;                             \
    bf16x8 b2 = *(const bf16x8*)&lds[32768 + so + oB[2]];            \
    bf16x8 b3 = *(const bf16x8*)&lds[32768 + so + oB[3]];            \
    PRE_STMT;                                                        \
    STAGE_STMT;                                                      \
    VMSTMT;                                                          \
    __builtin_amdgcn_s_barrier();                                    \
    POST_STMT;                                                       \
    __builtin_amdgcn_s_setprio(1);                                   \
    _Pragma("unroll") for (int m = 0; m < 8; ++m) {                  \
      acc[m][2] = MFMA_BF16(ACUR[m], b2, acc[m][2], 0, 0, 0);        \
      acc[m][3] = MFMA_BF16(ACUR[m], b3, acc[m][3], 0, 0, 0);        \
    }                                                                \
    __builtin_amdgcn_s_setprio(0);                                   \
  }

template <int OUTB, int ACT, int BIASM>
__global__ __launch_bounds__(512, 2)
void gemm8(const u16* __restrict__ A, const u16* __restrict__ Bt,
           const float* __restrict__ bias, int bias_n,
           void* __restrict__ Cout, int M, int Nc, int K) {
  __shared__ __align__(16) u16 lds[65536];  // A slots [0,32768), B slots [32768,65536)

  const int nbn = Nc >> 8, nbm = M >> 8;
  const int nwg = nbm * nbn;
  int bid = blockIdx.x;
  {  // bijective XCD swizzle (m204): XCD k owns a contiguous new-bid range
    int q = nwg >> 3, r = nwg & 7;
    int xcd = bid & 7, loc = bid >> 3;
    bid = (xcd < r ? xcd * (q + 1) : r * (q + 1) + (xcd - r) * q) + loc;
  }
  // 8x8 super-tile decode: contiguous 64-bid chunks -> compact 2D regions
  const int ns_n = nbn >> 3;
  const int sid = bid >> 6, idx = bid & 63;
  const int bm = ((sid / ns_n) << 3) + (idx >> 3);
  const int bn = ((sid % ns_n) << 3) + (idx & 7);
  const size_t row0 = (size_t)bm << 8, col0 = (size_t)bn << 8;

  const int tid = threadIdx.x;
  const int lane = tid & 63, wid = tid >> 6;
  const int wr = (wid >> 2) * 128, wc = (wid & 3) * 64;  // 2x4 waves, 128x64 each
  const int g = lane >> 4, r15 = lane & 15;

  // LDS read offsets (u16 units) within a [256][32] slot, chunk-XOR swizzled
  int oA[8], oB[4];
#pragma unroll
  for (int m = 0; m < 8; ++m) {
    int row = wr + m * 16 + r15;
    oA[m] = row * 32 + (g ^ ((row >> 1) & 3)) * 8;
  }
#pragma unroll
  for (int i = 0; i < 4; ++i) {
    int row = wc + (i >> 1) * 32 + (i & 1) * 16 + r15;
    oB[i] = row * 32 + (g ^ ((row >> 1) & 3)) * 8;
  }

  // staging source pointers (pre-swizzled global chunks, rule #21)
  const int r0 = tid >> 2, p0 = tid & 3;
  const int r1 = (512 + tid) >> 2, p1 = (512 + tid) & 3;
  const int c0 = p0 ^ ((r0 >> 1) & 3), c1 = p1 ^ ((r1 >> 1) & 3);
  const u16* As0 = A + (row0 + r0) * (size_t)K + c0 * 8;
  const u16* As1 = A + (row0 + r1) * (size_t)K + c1 * 8;
  const u16* Bs0 = Bt + (col0 + r0) * (size_t)K + c0 * 8;
  const u16* Bs1 = Bt + (col0 + r1) * (size_t)K + c1 * 8;

  auto stA = [&](int tb, int kk, int t) {
    size_t off = (size_t)t * 64 + kk * 32;
    u16* l = (u16*)lds + (tb * 2 + kk) * 8192 + wid * 512;
    __builtin_amdgcn_global_load_lds((const __attribute__((address_space(1))) void*)(As0 + off),
                                     (__attribute__((address_space(3))) void*)l, 16, 0, 0);
    __builtin_amdgcn_global_load_lds((const __attribute__((address_space(1))) void*)(As1 + off),
                                     (__attribute__((address_space(3))) void*)(l + 4096), 16, 0, 0);
  };
  auto stB = [&](int tb, int kk, int t) {
    size_t off = (size_t)t * 64 + kk * 32;
    u16* l = (u16*)lds + 32768 + (tb * 2 + kk) * 8192 + wid * 512;
    __builtin_amdgcn_global_load_lds((const __attribute__((address_space(1))) void*)(Bs0 + off),
                                     (__attribute__((address_space(3))) void*)l, 16, 0, 0);
    __builtin_amdgcn_global_load_lds((const __attribute__((address_space(1))) void*)(Bs1 + off),
                                     (__attribute__((address_space(3))) void*)(l + 4096), 16, 0, 0);
  };

  f32x4 acc[8][4];
#pragma unroll
  for (int m = 0; m < 8; ++m)
#pragma unroll
    for (int n = 0; n < 4; ++n)
#pragma unroll
      for (int i = 0; i < 4; ++i) acc[m][n][i] = 0.f;

  bf16x8 aX[8], aY[8];

  const int NT = K >> 6;       // 64-wide K tiles
  const int NI = K >> 7;       // 2 tiles per iteration

  // prologue: tile0 (both halves -> tb0), tile1 k0 -> tb1
  stA(0, 0, 0); stB(0, 0, 0);
  stA(0, 1, 0); stB(0, 1, 0);
  stA(1, 0, 1); stB(1, 0, 1);
  VM4;  // tile0 fully landed; tile1.k0 may be in flight
  __builtin_amdgcn_s_barrier();
  __builtin_amdgcn_sched_barrier(0);
  LDA4(aX, 0, 0)  // slot (0,0) A[0..3]

  for (int it = 0; it < NI; ++it) {
    const int u = 2 * it;
    const int t1 = u + 1;
    const int t2 = (u + 2 < NT) ? u + 2 : NT - 1;
    const int t3 = (u + 3 < NT) ? u + 3 : NT - 1;
    // p1: TB0 KK0 NH0
    P_N0(0, 0, aX, stA(1, 1, t1), NOVM)
    // p2: TB0 KK0 NH1; VM6 then pre-read aY<-(0,1)
    P_N1(0, 0, aX, VM6; LDA4(aY, 8192, 0), stB(1, 1, t1), NOVM, NOSTMT)
    // p3: TB0 KK1 NH0
    P_N0(0, 1, aY, stA(0, 0, t2), NOVM)
    // p4: TB0 KK1 NH1; VM6; post-read aX<-(1,0)
    P_N1(0, 1, aY, NOSTMT, stB(0, 0, t2), VM6,
         __builtin_amdgcn_sched_barrier(0); LDA4(aX, 16384, 0))
    // p5: TB1 KK0 NH0
    P_N0(1, 0, aX, stA(0, 1, t2), NOVM)
    // p6: TB1 KK0 NH1; VM6 then pre-read aY<-(1,1)
    P_N1(1, 0, aX, VM6; LDA4(aY, 24576, 0), stB(0, 1, t2), NOVM, NOSTMT)
    // p7: TB1 KK1 NH0
    P_N0(1, 1, aY, stA(1, 0, t3), NOVM)
    // p8: TB1 KK1 NH1; VM6; post-read aX<-(0,0)
    P_N1(1, 1, aY, NOSTMT, stB(1, 0, t3), VM6,
         __builtin_amdgcn_sched_barrier(0); LDA4(aX, 0, 0))
  }

  // epilogue: D col = lane&15, row = 4*(lane>>4) + reg (m89/m91 verified)
  const int rB = g << 2;
  const int cB = r15;
#pragma unroll
  for (int m = 0; m < 8; ++m) {
#pragma unroll
    for (int n = 0; n < 4; ++n) {
      size_t rr0 = row0 + wr + m * 16 + rB;
      size_t cc = col0 + wc + n * 16 + cB;
      float bc = (BIASM == 2) ? bias[cc] : 0.f;
#pragma unroll
      for (int i = 0; i < 4; ++i) {
        size_t r = rr0 + i;
        float v = acc[m][n][i];
        if (BIASM == 1) v += (r < (size_t)bias_n) ? bias[r] : 0.f;
        if (BIASM == 2) v += bc;
        if (ACT == 1) v = fmaxf(v, 0.f);
        if (OUTB) ((u16*)Cout)[r * (size_t)Nc + cc] = f2b(v);
        else      ((float*)Cout)[r * (size_t)Nc + cc] = v;
      }
    }
  }
}

// ------------- 128x128 split-K GEMM: Cpart[s] = A[:,k0:k0+Klen] @ Bt^T -------
// Only writes the live region [0,mw) x [0,nw) of each partial.
__global__ __launch_bounds__(256)
void gemm_splitk(const u16* __restrict__ A, const u16* __restrict__ Bt,
                 float* __restrict__ Cpart, int M, int Nc, int Kstride, int Klen,
                 int mw, int nw) {
  constexpr int BM = 128, BN = 128, BK = 32;
  __shared__ __align__(16) u16 As[2][BM * BK];
  __shared__ __align__(16) u16 Bs[2][BN * BK];

  const int nbn = Nc / BN;
  const int bid = blockIdx.x;
  const int s = blockIdx.y;
  const int k0 = s * Klen;
  const int bm = bid / nbn, bn = bid % nbn;
  const size_t row0 = (size_t)bm * BM, col0 = (size_t)bn * BN;

  const int tid = threadIdx.x;
  const int lane = tid & 63, wid = tid >> 6;
  const int wr = (wid >> 1) << 6, wc = (wid & 1) << 6;

  f32x4 acc[4][4];
#pragma unroll
  for (int m = 0; m < 4; ++m)
#pragma unroll
    for (int n = 0; n < 4; ++n)
#pragma unroll
      for (int i = 0; i < 4; ++i) acc[m][n][i] = 0.f;

  const int NT = Klen / BK;

  auto stage = [&](int buf, int t) {
    const int kk = k0 + t * BK;
#pragma unroll
    for (int i = 0; i < 2; ++i) {
      int lin = i * 256 + tid;
      int r = lin >> 2, c = lin & 3;
      int cs = c ^ ((r >> 1) & 3);
      const u16* ga = A + (row0 + r) * (size_t)Kstride + (size_t)(kk + cs * 8);
      u16* la = (u16*)As[buf] + (size_t)(i * 256 + (wid << 6)) * 8;
      __builtin_amdgcn_global_load_lds((const __attribute__((address_space(1))) void*)ga,
                                       (__attribute__((address_space(3))) void*)la, 16, 0, 0);
      const u16* gb = Bt + (col0 + r) * (size_t)Kstride + (size_t)(kk + cs * 8);
      u16* lb = (u16*)Bs[buf] + (size_t)(i * 256 + (wid << 6)) * 8;
      __builtin_amdgcn_global_load_lds((const __attribute__((address_space(1))) void*)gb,
                                       (__attribute__((address_space(3))) void*)lb, 16, 0, 0);
    }
  };

  stage(0, 0);
  __syncthreads();
  int cur = 0;
  for (int t = 0; t < NT; ++t) {
    if (t + 1 < NT) stage(cur ^ 1, t + 1);
    const int g = lane >> 4, r15 = lane & 15;
    bf16x8 af[4], bfv[4];
#pragma unroll
    for (int m = 0; m < 4; ++m) {
      int rr = wr + m * 16 + r15;
      int sc = g ^ ((rr >> 1) & 3);
      af[m] = *(const bf16x8*)(As[cur] + rr * BK + sc * 8);
    }
#pragma unroll
    for (int n = 0; n < 4; ++n) {
      int rr = wc + n * 16 + r15;
      int sc = g ^ ((rr >> 1) & 3);
      bfv[n] = *(const bf16x8*)(Bs[cur] + rr * BK + sc * 8);
    }
#pragma unroll
    for (int m = 0; m < 4; ++m)
#pragma unroll
      for (int n = 0; n < 4; ++n)
        acc[m][n] = __builtin_amdgcn_mfma_f32_16x16x32_bf16(af[m], bfv[n], acc[m][n], 0, 0, 0);
    __syncthreads();
    cur ^= 1;
  }

  float* Cp = Cpart + (size_t)s * M * Nc;
  const int rB = (lane >> 4) << 2;
  const int cB = lane & 15;
#pragma unroll
  for (int m = 0; m < 4; ++m) {
#pragma unroll
    for (int n = 0; n < 4; ++n) {
      size_t rr0 = row0 + wr + m * 16 + rB;
      size_t cc = col0 + wc + n * 16 + cB;
      if ((int)rr0 < mw && (int)cc < nw) {
#pragma unroll
        for (int i = 0; i < 4; ++i)
          Cp[(rr0 + i) * (size_t)Nc + cc] = acc[m][n][i];
      }
    }
  }
}

// ---- reduce 8 partials [128][8192] rows<64 + b2 -> t2T bf16 (rows>=64 zero) ----
__global__ void k_red3(const float* __restrict__ part, const float* __restrict__ b2,
                       u16* __restrict__ t2T) {
  int i = blockIdx.x * 256 + threadIdx.x;
  size_t idx = (size_t)i * 4;
  int r = (int)(idx >> 13);
  u16x4 o;
  if (r < 64) {
    f32x4 s = *(const f32x4*)(part + idx);
#pragma unroll
    for (int ss = 1; ss < 8; ++ss) {
      f32x4 p = *(const f32x4*)(part + (size_t)ss * 1048576 + idx);
      s[0] += p[0]; s[1] += p[1]; s[2] += p[2]; s[3] += p[3];
    }
    float b = b2[r];
    o[0] = f2b(s[0] + b); o[1] = f2b(s[1] + b); o[2] = f2b(s[2] + b); o[3] = f2b(s[3] + b);
  } else {
    o[0] = 0; o[1] = 0; o[2] = 0; o[3] = 0;
  }
  *(u16x4*)(t2T + idx) = o;
}

// ---- fused: reduce 8 partials -> code = tanh(10*sum); LN + RBF + silu -> Acat ----
__global__ void k_red4kan(const float* __restrict__ part, const float* __restrict__ lng,
                          const float* __restrict__ lnb, float* __restrict__ code,
                          u16* __restrict__ Acat) {
  int row = blockIdx.x * 4 + (threadIdx.x >> 6);
  int c = threadIdx.x & 63;
  size_t idx = (size_t)row * 128 + c;
  float sm = 0.f;
#pragma unroll
  for (int ss = 0; ss < 8; ++ss) sm += part[(size_t)ss * 1048576 + idx];
  float xv = tanhf(10.f * sm);
  code[(size_t)row * 64 + c] = xv;
  float s = xv, s2 = xv * xv;
#pragma unroll
  for (int m = 32; m; m >>= 1) { s += __shfl_xor(s, m); s2 += __shfl_xor(s2, m); }
  float mean = s * 0.015625f;
  float var = s2 * 0.015625f - mean * mean;
  float z = (xv - mean) * rsqrtf(var + 1e-5f) * lng[c] + lnb[c];
  u16x8 o;
#pragma unroll
  for (int gi = 0; gi < 8; ++gi) {
    float gp = -2.f + gi * (4.f / 7.f);
    float d = (z - gp) * (7.f / 4.f);
    o[gi] = f2b(expf(-d * d));
  }
  *(u16x8*)(Acat + (size_t)row * 640 + c * 8) = o;
  float si = xv / (1.f + expf(-xv));
  Acat[(size_t)row * 640 + 512 + c] = f2b(si);
  Acat[(size_t)row * 640 + 576 + c] = 0;  // K-pad
}

// ---------------- Bcat[8192][640] = [Ws | Wb | 0] bf16 ----------------
__global__ void k_bcat(const float* __restrict__ Ws, const float* __restrict__ Wb,
                       u16* __restrict__ Bcat) {
  int i = blockIdx.x * 256 + threadIdx.x;
  int n = i / 80, j = i % 80;
  u16x8 o;
  if (j < 72) {
    const float* src = (j < 64) ? (Ws + (size_t)n * 512 + j * 8)
                                : (Wb + (size_t)n * 64 + (j - 64) * 8);
    f32x4 a = *(const f32x4*)src, b = *(const f32x4*)(src + 4);
    o[0] = f2b(a[0]); o[1] = f2b(a[1]); o[2] = f2b(a[2]); o[3] = f2b(a[3]);
    o[4] = f2b(b[0]); o[5] = f2b(b[1]); o[6] = f2b(b[2]); o[7] = f2b(b[3]);
  } else {
    o = (u16x8)0;
  }
  *(u16x8*)(Bcat + (size_t)n * 640 + j * 8) = o;
}

extern "C" void kernel_launch(void* const* d_in, const int* in_sizes, int n_in,
                              void* d_out, int out_size, void* d_ws, size_t ws_size,
                              hipStream_t stream) {
  const float* x   = (const float*)d_in[0];
  const float* G   = (const float*)d_in[1];
  const float* W1  = (const float*)d_in[2];
  const float* b1  = (const float*)d_in[3];
  const float* W2  = (const float*)d_in[4];
  const float* b2  = (const float*)d_in[5];
  const float* lng = (const float*)d_in[6];
  const float* lnb = (const float*)d_in[7];
  const float* Ws  = (const float*)d_in[8];
  const float* Wb  = (const float*)d_in[9];
  const float* bb  = (const float*)d_in[10];

  uint8_t* w = (uint8_t*)d_ws;
  u16* G_b  = (u16*)w;                   // [8192][8192] bf16  [0,128M)
  u16* x_b  = (u16*)(w + 134217728);     // [8192][4096] bf16  [128M,192M)
  u16* h_b  = x_b;                       // reuse after step1
  uint8_t* r2 = w + 201326592;           // [192M,224M)
  u16* W1T  = (u16*)r2;                  // [4096][4096] (dead after step1)
  u16* t2T  = (u16*)r2;                  // [128][8192]  (after W1T dead)
  u16* Acat = (u16*)(r2 + 8388608);      // [8192][640]
  u16* Bcat = (u16*)(r2 + 18874368);     // [8192][640]
  u16* t1T  = (u16*)(w + 234881024);     // [4096][8192] (dead after step2)
  u16* W2T  = t1T;                       // [128][4096] reuses t1T space
  float* part = (float*)(w + 234881024 + 2097152);  // 8x[128][8192] f32

  float* code_out = (float*)d_out;              // [8192][64]
  float* out1 = (float*)d_out + 524288;         // [8192][8192]

  // conversions
  k_f2b<<<32768, 256, 0, stream>>>(G, G_b, 8388608);
  k_f2b<<<16384, 256, 0, stream>>>(x, x_b, 4194304);
  k_trans_f2b<<<dim3(128, 128), dim3(32, 8), 0, stream>>>(W1, W1T, 4096, 4096, 4096);

  // step1: t1T[4096][8192] = W1T @ x^T + b1(row)   (nbm=16, nbn=32)
  gemm8<1, 0, 1><<<512, 512, 0, stream>>>(W1T, x_b, b1, 4096, t1T, 4096, 8192, 4096);
  // step2: h[8192][4096] = relu(G @ t1)            (nbm=32, nbn=16)
  gemm8<1, 1, 0><<<512, 512, 0, stream>>>(G_b, t1T, nullptr, 0, h_b, 8192, 4096, 8192);
  // W2T [128][4096] (rows 64..127 zero)
  k_trans_f2b<<<dim3(4, 128), dim3(32, 8), 0, stream>>>(W2, W2T, 4096, 64, 128);
  // step3 (split-K x8): part[s] = W2T @ h^T chunk (rows<64 live)
  gemm_splitk<<<dim3(64, 8), 256, 0, stream>>>(W2T, h_b, part, 128, 8192, 4096, 512, 64, 8192);
  // reduce + b2 -> t2T bf16
  k_red3<<<1024, 256, 0, stream>>>(part, b2, t2T);
  // step4 (split-K x8): part[s] = G @ t2 chunk (cols<64 live)
  gemm_splitk<<<dim3(64, 8), 256, 0, stream>>>(G_b, t2T, part, 8192, 128, 8192, 1024, 8192, 64);
  // fused reduce -> code = tanh(10*feat); LN + RBF + silu -> Acat
  k_red4kan<<<2048, 256, 0, stream>>>(part, lng, lnb, code_out, Acat);
  // Bcat = [Ws | Wb | 0]
  k_bcat<<<2560, 256, 0, stream>>>(Ws, Wb, Bcat);
  // final: out = relu(Acat @ Bcat^T + bb(col))     (nbm=32, nbn=32)
  gemm8<0, 1, 2><<<1024, 512, 0, stream>>>(Acat, Bcat, bb, 8192, out1, 8192, 8192, 640);
}